// Round 1
// baseline (758.893 us; speedup 1.0000x reference)
//
#include <hip/hip_runtime.h>

#define CIN 256
#define HIDDEN 64
#define HALF 32

// One thread = one pixel. Fuses conv1(256->64), split/relu/concat (->96),
// conv2(96->256). All weight indices are wave-uniform -> scalar loads; the
// inner loops are pure v_fmac_f32 with SGPR weight operands.
template<int HW>
__device__ __forceinline__ void level_body(
    const float* __restrict__ x,
    const float* __restrict__ W1,
    const float* __restrict__ b1,
    const float* __restrict__ W2,
    const float* __restrict__ b2,
    float* __restrict__ out,
    int blk)
{
    const int q = blk * 256 + (int)threadIdx.x;   // pixel id in [0, 4*HW)
    const int b = q / HW;                          // HW = 2^k -> shift
    const int p = q - b * HW;
    const float* xb = x + (size_t)b * CIN * HW + p;
    float*       ob = out + (size_t)b * CIN * HW + p;

    float y[HIDDEN];
#pragma unroll
    for (int j = 0; j < HIDDEN; ++j) y[j] = b1[j];

    // ---- stage 1: y = W1^T x + b1, software-pipelined x loads (8 ahead) ----
    float xa[8];
#pragma unroll
    for (int u = 0; u < 8; ++u) xa[u] = xb[(size_t)u * HW];

    for (int c0 = 0; c0 < CIN; c0 += 8) {
        float xn[8];
        if (c0 + 8 < CIN) {
#pragma unroll
            for (int u = 0; u < 8; ++u) xn[u] = xb[(size_t)(c0 + 8 + u) * HW];
        }
#pragma unroll
        for (int u = 0; u < 8; ++u) {
#pragma unroll
            for (int j = 0; j < HIDDEN; ++j)
                y[j] = fmaf(xa[u], W1[(c0 + u) * HIDDEN + j], y[j]);
        }
#pragma unroll
        for (int u = 0; u < 8; ++u) xa[u] = xn[u];
    }

    // z = [y[0:32], y[32:64], relu(y[32:64])]
    float r[HALF];
#pragma unroll
    for (int k = 0; k < HALF; ++k) r[k] = fmaxf(y[HALF + k], 0.0f);

    // ---- stage 2: o = W2^T z + b2, 16 output channels at a time ----
    for (int d0 = 0; d0 < CIN; d0 += 16) {
        float acc[16];
#pragma unroll
        for (int i = 0; i < 16; ++i) acc[i] = b2[d0 + i];
#pragma unroll
        for (int k = 0; k < HALF; ++k) {
            const float z0 = y[k];
            const float z1 = y[HALF + k];
            const float z2 = r[k];
#pragma unroll
            for (int i = 0; i < 16; ++i) {
                acc[i] = fmaf(z0, W2[k * CIN + d0 + i],            acc[i]);
                acc[i] = fmaf(z1, W2[(HALF + k) * CIN + d0 + i],   acc[i]);
                acc[i] = fmaf(z2, W2[(HIDDEN + k) * CIN + d0 + i], acc[i]);
            }
        }
#pragma unroll
        for (int i = 0; i < 16; ++i)
            ob[(size_t)(d0 + i) * HW] = acc[i];
    }
}

__global__ __launch_bounds__(256, 2) void fused_all(
    const float* x0, const float* x1, const float* x2,
    const float* W1_0, const float* b1_0, const float* W2_0, const float* b2_0,
    const float* W1_1, const float* b1_1, const float* W2_1, const float* b2_1,
    const float* W1_2, const float* b1_2, const float* W2_2, const float* b2_2,
    float* out)
{
    const int blk = (int)blockIdx.x;
    // level 0: 65536 px -> 256 blocks; level 1: 16384 px -> 64; level 2: 4096 px -> 16
    if (blk < 256) {
        level_body<16384>(x0, W1_0, b1_0, W2_0, b2_0, out, blk);
    } else if (blk < 320) {
        level_body<4096>(x1, W1_1, b1_1, W2_1, b2_1,
                         out + (size_t)4 * CIN * 16384, blk - 256);
    } else {
        level_body<1024>(x2, W1_2, b1_2, W2_2, b2_2,
                         out + (size_t)4 * CIN * 16384 + (size_t)4 * CIN * 4096,
                         blk - 320);
    }
}

extern "C" void kernel_launch(void* const* d_in, const int* in_sizes, int n_in,
                              void* d_out, int out_size, void* d_ws, size_t ws_size,
                              hipStream_t stream) {
    const float* x0   = (const float*)d_in[0];
    const float* x1   = (const float*)d_in[1];
    const float* x2   = (const float*)d_in[2];
    const float* W1_0 = (const float*)d_in[3];
    const float* b1_0 = (const float*)d_in[4];
    const float* W2_0 = (const float*)d_in[5];
    const float* b2_0 = (const float*)d_in[6];
    const float* W1_1 = (const float*)d_in[7];
    const float* b1_1 = (const float*)d_in[8];
    const float* W2_1 = (const float*)d_in[9];
    const float* b2_1 = (const float*)d_in[10];
    const float* W1_2 = (const float*)d_in[11];
    const float* b1_2 = (const float*)d_in[12];
    const float* W2_2 = (const float*)d_in[13];
    const float* b2_2 = (const float*)d_in[14];
    float* out = (float*)d_out;

    dim3 grid(336), block(256);
    fused_all<<<grid, block, 0, stream>>>(
        x0, x1, x2,
        W1_0, b1_0, W2_0, b2_0,
        W1_1, b1_1, W2_1, b2_1,
        W1_2, b1_2, W2_2, b2_2,
        out);
}

// Round 2
// 208.995 us; speedup vs baseline: 3.6312x; 3.6312x over previous
//
#include <hip/hip_runtime.h>

typedef __attribute__((ext_vector_type(8))) short short8;
typedef __attribute__((ext_vector_type(4))) float float4v;

__device__ __forceinline__ unsigned short f2bf(float f) {
    unsigned u = __float_as_uint(f);
    u = (u + 0x7FFFu + ((u >> 16) & 1u)) >> 16;
    return (unsigned short)u;
}

// ---------------------------------------------------------------------------
// Prepack: W1 [256x64] and W2 [96x256] (both [cin,cout]) -> bf16 in MFMA
// A-operand fragment order. A[m][k]: m = lane&15, k = (lane>>4)*8 + j.
// A1 layout: ((mt*8 + ks)*64 + lane)*8 + j   (mt in 0..3,  ks in 0..7)
// A2 layout: ((mt*3 + ks)*64 + lane)*8 + j   (mt in 0..15, ks in 0..2)
// Per level: 16384 + 24576 = 40960 ushorts. 3 levels -> 245760 B in d_ws.
// ---------------------------------------------------------------------------
__global__ void prepack(const float* __restrict__ W1_0, const float* __restrict__ W2_0,
                        const float* __restrict__ W1_1, const float* __restrict__ W2_1,
                        const float* __restrict__ W1_2, const float* __restrict__ W2_2,
                        unsigned short* __restrict__ ws) {
    int e = blockIdx.x * 256 + threadIdx.x;
    if (e >= 3 * 40960) return;
    int l = e / 40960, r = e % 40960;
    const float* W1 = (l == 0) ? W1_0 : (l == 1) ? W1_1 : W1_2;
    const float* W2 = (l == 0) ? W2_0 : (l == 1) ? W2_1 : W2_2;
    unsigned short* base = ws + l * 40960;
    if (r < 16384) {
        int j = r & 7, lane = (r >> 3) & 63, fs = r >> 9;
        int mt = fs >> 3, ks = fs & 7;
        int k = ks * 32 + (lane >> 4) * 8 + j;
        int m = mt * 16 + (lane & 15);
        base[r] = f2bf(W1[k * 64 + m]);
    } else {
        int r2 = r - 16384;
        int j = r2 & 7, lane = (r2 >> 3) & 63, fs = r2 >> 9;
        int mt = fs / 3, ks = fs - mt * 3;
        int k = ks * 32 + (lane >> 4) * 8 + j;
        int m = mt * 16 + (lane & 15);
        base[16384 + r2] = f2bf(W2[k * 256 + m]);
    }
}

// ---------------------------------------------------------------------------
// Main fused kernel. One wave = 16 pixels. M = out-channels, N = pixels,
// K = in-channels. Stage1: y[64,16] = W1^T x. Stage2: o[256,16] = W2^T z,
// z = [y0:32, y32:64, relu(y32:64)] relayout C->B via wave-private LDS.
// ---------------------------------------------------------------------------
template<int HW>
__device__ __forceinline__ void level_mfma(
    const float* __restrict__ x,          // this batch: [256][HW]
    const unsigned short* __restrict__ A1,
    const unsigned short* __restrict__ A2,
    const float* __restrict__ b1,
    const float* __restrict__ b2,
    float* __restrict__ o,                // this batch: [256][HW]
    int px0,                              // wave's base pixel
    unsigned short* __restrict__ zs)      // wave-private LDS: [16][104]
{
    const int lane = (int)threadIdx.x & 63;
    const int q = lane >> 4, n = lane & 15;
    const int pxg = px0 + n;
    const float* xb = x + pxg;

    // ---- stage 1: acc1[mt] = bias, then 8 k-steps x 4 m-tiles of MFMA ----
    float4v acc1[4];
#pragma unroll
    for (int mt = 0; mt < 4; ++mt)
        acc1[mt] = *(const float4v*)(b1 + mt * 16 + q * 4);

    short8 xf[8];   // B-frags: B[k][n], k = q*8+j within each 32-chunk
#pragma unroll
    for (int ks = 0; ks < 8; ++ks) {
        float xv[8];
#pragma unroll
        for (int j = 0; j < 8; ++j)
            xv[j] = xb[(size_t)(ks * 32 + q * 8 + j) * HW];
        short8 f;
#pragma unroll
        for (int j = 0; j < 8; ++j) f[j] = (short)f2bf(xv[j]);
        xf[ks] = f;
    }

    const short8* A1f = (const short8*)A1;
#pragma unroll
    for (int ks = 0; ks < 8; ++ks) {
#pragma unroll
        for (int mt = 0; mt < 4; ++mt) {
            short8 a = A1f[(mt * 8 + ks) * 64 + lane];
            acc1[mt] = __builtin_amdgcn_mfma_f32_16x16x32_bf16(a, xf[ks], acc1[mt], 0, 0, 0);
        }
    }

    // ---- C-layout -> B-layout via wave-private LDS (no barrier needed) ----
    // C: col(pixel) = n, row(channel-in-tile) = q*4 + reg.
    unsigned int* zrow = (unsigned int*)(zs + n * 104);
#pragma unroll
    for (int mt = 0; mt < 4; ++mt) {
        int ch = mt * 16 + q * 4;
        unsigned p0 = (unsigned)f2bf(acc1[mt][0]) | ((unsigned)f2bf(acc1[mt][1]) << 16);
        unsigned p1 = (unsigned)f2bf(acc1[mt][2]) | ((unsigned)f2bf(acc1[mt][3]) << 16);
        zrow[(ch >> 1) + 0] = p0;
        zrow[(ch >> 1) + 1] = p1;
        if (mt >= 2) {  // channels 32..63 -> relu copy at 64..95
            unsigned r0 = (unsigned)f2bf(fmaxf(acc1[mt][0], 0.f)) |
                          ((unsigned)f2bf(fmaxf(acc1[mt][1], 0.f)) << 16);
            unsigned r1 = (unsigned)f2bf(fmaxf(acc1[mt][2], 0.f)) |
                          ((unsigned)f2bf(fmaxf(acc1[mt][3], 0.f)) << 16);
            zrow[((ch + 32) >> 1) + 0] = r0;
            zrow[((ch + 32) >> 1) + 1] = r1;
        }
    }

    // ---- stage 2: 3 k-steps x 16 m-tiles ----
    float4v acc2[16];
#pragma unroll
    for (int mt = 0; mt < 16; ++mt)
        acc2[mt] = *(const float4v*)(b2 + mt * 16 + q * 4);

    short8 zf[3];
#pragma unroll
    for (int ks = 0; ks < 3; ++ks)
        zf[ks] = *(const short8*)(zs + n * 104 + ks * 32 + q * 8);

    const short8* A2f = (const short8*)A2;
#pragma unroll
    for (int ks = 0; ks < 3; ++ks) {
#pragma unroll
        for (int mt = 0; mt < 16; ++mt) {
            short8 a = A2f[(mt * 3 + ks) * 64 + lane];
            acc2[mt] = __builtin_amdgcn_mfma_f32_16x16x32_bf16(a, zf[ks], acc2[mt], 0, 0, 0);
        }
    }

    // ---- store: each inst writes 4 full 64B lines ----
    float* ob = o + pxg;
#pragma unroll
    for (int mt = 0; mt < 16; ++mt) {
#pragma unroll
        for (int r = 0; r < 4; ++r)
            ob[(size_t)(mt * 16 + q * 4 + r) * HW] = acc2[mt][r];
    }
}

__global__ __launch_bounds__(256, 2) void fused_mfma(
    const float* __restrict__ x0, const float* __restrict__ x1, const float* __restrict__ x2,
    const float* __restrict__ b1_0, const float* __restrict__ b2_0,
    const float* __restrict__ b1_1, const float* __restrict__ b2_1,
    const float* __restrict__ b1_2, const float* __restrict__ b2_2,
    const unsigned short* __restrict__ wpk, float* __restrict__ out)
{
    __shared__ unsigned short zs[4][16 * 104];   // 13.3 KB, wave-private slices
    const int wv = (int)threadIdx.x >> 6;
    const int bi = (int)blockIdx.x;

    if (bi < 1024) {                       // level 0: 4 x 256 tiles
        int b = bi >> 8, t = bi & 255;
        level_mfma<16384>(x0 + (size_t)b * 256 * 16384,
                          wpk + 0, wpk + 16384, b1_0, b2_0,
                          out + (size_t)b * 256 * 16384,
                          t * 64 + wv * 16, zs[wv]);
    } else if (bi < 1280) {                // level 1: 4 x 64 tiles
        int r = bi - 1024, b = r >> 6, t = r & 63;
        level_mfma<4096>(x1 + (size_t)b * 256 * 4096,
                         wpk + 40960, wpk + 40960 + 16384, b1_1, b2_1,
                         out + 16777216 + (size_t)b * 256 * 4096,
                         t * 64 + wv * 16, zs[wv]);
    } else {                               // level 2: 4 x 16 tiles
        int r = bi - 1280, b = r >> 4, t = r & 15;
        level_mfma<1024>(x2 + (size_t)b * 256 * 1024,
                         wpk + 81920, wpk + 81920 + 16384, b1_2, b2_2,
                         out + 20971520 + (size_t)b * 256 * 1024,
                         t * 64 + wv * 16, zs[wv]);
    }
}

extern "C" void kernel_launch(void* const* d_in, const int* in_sizes, int n_in,
                              void* d_out, int out_size, void* d_ws, size_t ws_size,
                              hipStream_t stream) {
    const float* x0   = (const float*)d_in[0];
    const float* x1   = (const float*)d_in[1];
    const float* x2   = (const float*)d_in[2];
    const float* W1_0 = (const float*)d_in[3];
    const float* b1_0 = (const float*)d_in[4];
    const float* W2_0 = (const float*)d_in[5];
    const float* b2_0 = (const float*)d_in[6];
    const float* W1_1 = (const float*)d_in[7];
    const float* b1_1 = (const float*)d_in[8];
    const float* W2_1 = (const float*)d_in[9];
    const float* b2_1 = (const float*)d_in[10];
    const float* W1_2 = (const float*)d_in[11];
    const float* b1_2 = (const float*)d_in[12];
    const float* W2_2 = (const float*)d_in[13];
    const float* b2_2 = (const float*)d_in[14];
    float* out = (float*)d_out;
    unsigned short* wpk = (unsigned short*)d_ws;   // needs 245760 B

    prepack<<<dim3(480), dim3(256), 0, stream>>>(W1_0, W2_0, W1_1, W2_1, W1_2, W2_2, wpk);
    fused_mfma<<<dim3(1344), dim3(256), 0, stream>>>(
        x0, x1, x2, b1_0, b2_0, b1_1, b2_1, b1_2, b2_2, wpk, out);
}

// Round 3
// 193.058 us; speedup vs baseline: 3.9309x; 1.0826x over previous
//
#include <hip/hip_runtime.h>

typedef __attribute__((ext_vector_type(8))) short short8;
typedef __attribute__((ext_vector_type(4))) float float4v;

__device__ __forceinline__ unsigned short f2bf(float f) {
    unsigned u = __float_as_uint(f);
    u = (u + 0x7FFFu + ((u >> 16) & 1u)) >> 16;
    return (unsigned short)u;
}

#define XSET 520   // 512 data + 8 pad ushorts per (g,ks) fragment set
#define CROW 68    // 64 px + 4 pad floats per staged C row
#define CS_BYTES 34816   // 4 waves * 32 ch * CROW * 4B  (aliases x region)
#define ZS_BYTES 12480   // 12 sets * XSET * 2B

// ---------------------------------------------------------------------------
// Prepack: W1 [256x64], W2 [96x256] ([cin,cout]) -> bf16 MFMA A-frag order.
// A[m][k]: m = lane&15, k = (lane>>4)*8 + j.
// A1: ((mt*8 + ks)*64 + lane)*8 + j   (mt 0..3,  ks 0..7)
// A2: ((mt*3 + ks)*64 + lane)*8 + j   (mt 0..15, ks 0..2)
// ---------------------------------------------------------------------------
__global__ void prepack(const float* __restrict__ W1_0, const float* __restrict__ W2_0,
                        const float* __restrict__ W1_1, const float* __restrict__ W2_1,
                        const float* __restrict__ W1_2, const float* __restrict__ W2_2,
                        unsigned short* __restrict__ ws) {
    int e = blockIdx.x * 256 + threadIdx.x;
    if (e >= 3 * 40960) return;
    int l = e / 40960, r = e % 40960;
    const float* W1 = (l == 0) ? W1_0 : (l == 1) ? W1_1 : W1_2;
    const float* W2 = (l == 0) ? W2_0 : (l == 1) ? W2_1 : W2_2;
    unsigned short* base = ws + l * 40960;
    if (r < 16384) {
        int j = r & 7, lane = (r >> 3) & 63, fs = r >> 9;
        int mt = fs >> 3, ks = fs & 7;
        int k = ks * 32 + (lane >> 4) * 8 + j;
        int m = mt * 16 + (lane & 15);
        base[r] = f2bf(W1[k * 64 + m]);
    } else {
        int r2 = r - 16384;
        int j = r2 & 7, lane = (r2 >> 3) & 63, fs = r2 >> 9;
        int mt = fs / 3, ks = fs - mt * 3;
        int k = ks * 32 + (lane >> 4) * 8 + j;
        int m = mt * 16 + (lane & 15);
        base[16384 + r2] = f2bf(W2[k * 256 + m]);
    }
}

// ---------------------------------------------------------------------------
// Block = 256 thr (4 waves) = 64 px, all channels. All global I/O in >=256 B
// contiguous runs. Stage1: wave w computes y for px-group g=w; z-frags to
// shared LDS. Stage2: wave w computes out-ch 64w..64w+63 for ALL 64 px;
// C staged through LDS -> px-major nontemporal dwordx4 stores.
// ---------------------------------------------------------------------------
template<int HW>
__device__ __forceinline__ void level3(
    const float* __restrict__ x,           // this batch: [256][HW]
    const unsigned short* __restrict__ A1,
    const unsigned short* __restrict__ A2,
    const float* __restrict__ b1, const float* __restrict__ b2,
    float* __restrict__ o, int px0,
    unsigned short* __restrict__ xs,       // frag-layout x (aliased by cs)
    unsigned short* __restrict__ zs)       // frag-layout z
{
    const int t = (int)threadIdx.x;
    const int lane = t & 63, w = t >> 6;
    const int q = lane >> 4, n = lane & 15;

    // ---- phase 1: stage x [256 ch][64 px] -> bf16 frag layout in LDS ----
    {
        const int ch_lo = t >> 4;               // 0..15
        const int pp = t & 15;                  // px = 4*pp + e
        const int g = pp >> 2;
        const int n0 = (pp & 3) * 4;
        const float* xp = x + (size_t)ch_lo * HW + px0 + 4 * pp;
#pragma unroll
        for (int i = 0; i < 16; ++i) {
            const int ch = i * 16 + ch_lo;
            float4v v = *(const float4v*)(xp + (size_t)i * 16 * HW);
            const int ks = ch >> 5, qq = (ch >> 3) & 3, j = ch & 7;
            unsigned short* base = xs + (g * 8 + ks) * XSET + j;
#pragma unroll
            for (int e = 0; e < 4; ++e)
                base[(qq * 16 + n0 + e) * 8] = f2bf(v[e]);
        }
    }
    __syncthreads();

    // ---- stage 1: wave w -> px group g = w ----
    float4v acc1[4];
#pragma unroll
    for (int mt = 0; mt < 4; ++mt)
        acc1[mt] = *(const float4v*)(b1 + mt * 16 + q * 4);

    short8 xf[8];
#pragma unroll
    for (int ks = 0; ks < 8; ++ks)
        xf[ks] = *(const short8*)(xs + (w * 8 + ks) * XSET + lane * 8);

    const short8* A1f = (const short8*)A1;
#pragma unroll
    for (int ks = 0; ks < 8; ++ks)
#pragma unroll
        for (int mt = 0; mt < 4; ++mt)
            acc1[mt] = __builtin_amdgcn_mfma_f32_16x16x32_bf16(
                A1f[(mt * 8 + ks) * 64 + lane], xf[ks], acc1[mt], 0, 0, 0);

    // ---- z = [y, relu(y_hi)] -> shared frag-layout LDS (b64 packed) ----
    {
        unsigned short* zg = zs + w * 3 * XSET;
#pragma unroll
        for (int mt = 0; mt < 4; ++mt) {
            const int kb = mt * 16 + q * 4;   // C row = q*4+r = ch kb+r
            unsigned long long pk =
                  (unsigned long long)f2bf(acc1[mt][0])
                | ((unsigned long long)f2bf(acc1[mt][1]) << 16)
                | ((unsigned long long)f2bf(acc1[mt][2]) << 32)
                | ((unsigned long long)f2bf(acc1[mt][3]) << 48);
            *(unsigned long long*)(zg + (kb >> 5) * XSET +
                (((kb >> 3) & 3) * 16 + n) * 8 + (kb & 7)) = pk;
            if (mt >= 2) {
                const int kr = kb + 32;       // relu copy at k = 64 + (ch-32)
                unsigned long long pr =
                      (unsigned long long)f2bf(fmaxf(acc1[mt][0], 0.f))
                    | ((unsigned long long)f2bf(fmaxf(acc1[mt][1], 0.f)) << 16)
                    | ((unsigned long long)f2bf(fmaxf(acc1[mt][2], 0.f)) << 32)
                    | ((unsigned long long)f2bf(fmaxf(acc1[mt][3], 0.f)) << 48);
                *(unsigned long long*)(zg + (kr >> 5) * XSET +
                    (((kr >> 3) & 3) * 16 + n) * 8 + (kr & 7)) = pr;
            }
        }
    }
    __syncthreads();

    // ---- stage 2: wave w -> out-ch 64w..64w+63, all 4 px groups ----
    float4v acc2[4][4];   // [mm][g]
#pragma unroll
    for (int mm = 0; mm < 4; ++mm) {
        float4v bb = *(const float4v*)(b2 + (w * 4 + mm) * 16 + q * 4);
#pragma unroll
        for (int g = 0; g < 4; ++g) acc2[mm][g] = bb;
    }

    const short8* A2f = (const short8*)A2;
#pragma unroll
    for (int g = 0; g < 4; ++g) {
        short8 zf[3];
#pragma unroll
        for (int ks = 0; ks < 3; ++ks)
            zf[ks] = *(const short8*)(zs + (g * 3 + ks) * XSET + lane * 8);
#pragma unroll
        for (int ks = 0; ks < 3; ++ks)
#pragma unroll
            for (int mm = 0; mm < 4; ++mm)
                acc2[mm][g] = __builtin_amdgcn_mfma_f32_16x16x32_bf16(
                    A2f[((w * 4 + mm) * 3 + ks) * 64 + lane], zf[ks], acc2[mm][g], 0, 0, 0);
    }

    // ---- store: C -> LDS (wave-private slot) -> px-major nt dwordx4 ----
    float* cw = (float*)xs + w * 32 * CROW;   // aliases x region (post-barrier)
#pragma unroll
    for (int p = 0; p < 2; ++p) {
#pragma unroll
        for (int mp = 0; mp < 2; ++mp) {
            const int mm = p * 2 + mp;
#pragma unroll
            for (int g = 0; g < 4; ++g)
#pragma unroll
                for (int r = 0; r < 4; ++r)
                    cw[(mp * 16 + q * 4 + r) * CROW + g * 16 + n] = acc2[mm][g][r];
        }
        // wave-private slot: DS ops from one wave execute in order; no barrier
        const int chs = lane >> 4;            // 0..3
        const int pp = lane & 15;
        float* op = o + (size_t)(w * 64 + p * 32 + chs) * HW + px0 + 4 * pp;
#pragma unroll
        for (int i = 0; i < 8; ++i) {
            float4v v = *(const float4v*)(cw + (i * 4 + chs) * CROW + 4 * pp);
            __builtin_nontemporal_store(v, (float4v*)(op + (size_t)(i * 4) * HW));
        }
    }
}

__global__ __launch_bounds__(256, 3) void fused_v3(
    const float* __restrict__ x0, const float* __restrict__ x1, const float* __restrict__ x2,
    const float* __restrict__ b1_0, const float* __restrict__ b2_0,
    const float* __restrict__ b1_1, const float* __restrict__ b2_1,
    const float* __restrict__ b1_2, const float* __restrict__ b2_2,
    const unsigned short* __restrict__ wpk, float* __restrict__ out)
{
    __shared__ __align__(16) unsigned char smem[CS_BYTES + ZS_BYTES];
    unsigned short* xs = (unsigned short*)smem;            // x frags / C staging
    unsigned short* zs = (unsigned short*)(smem + CS_BYTES);
    const int bi = (int)blockIdx.x;

    if (bi < 1024) {                        // level 0: 4 batches x 256 tiles
        int b = bi >> 8, px0 = (bi & 255) * 64;
        level3<16384>(x0 + (size_t)b * 256 * 16384, wpk, wpk + 16384, b1_0, b2_0,
                      out + (size_t)b * 256 * 16384, px0, xs, zs);
    } else if (bi < 1280) {                 // level 1: 4 x 64 tiles
        int r = bi - 1024, b = r >> 6, px0 = (r & 63) * 64;
        level3<4096>(x1 + (size_t)b * 256 * 4096, wpk + 40960, wpk + 40960 + 16384,
                     b1_1, b2_1, out + 16777216 + (size_t)b * 256 * 4096, px0, xs, zs);
    } else {                                // level 2: 4 x 16 tiles
        int r = bi - 1280, b = r >> 4, px0 = (r & 15) * 64;
        level3<1024>(x2 + (size_t)b * 256 * 1024, wpk + 81920, wpk + 81920 + 16384,
                     b1_2, b2_2, out + 20971520 + (size_t)b * 256 * 1024, px0, xs, zs);
    }
}

extern "C" void kernel_launch(void* const* d_in, const int* in_sizes, int n_in,
                              void* d_out, int out_size, void* d_ws, size_t ws_size,
                              hipStream_t stream) {
    const float* x0   = (const float*)d_in[0];
    const float* x1   = (const float*)d_in[1];
    const float* x2   = (const float*)d_in[2];
    const float* W1_0 = (const float*)d_in[3];
    const float* b1_0 = (const float*)d_in[4];
    const float* W2_0 = (const float*)d_in[5];
    const float* b2_0 = (const float*)d_in[6];
    const float* W1_1 = (const float*)d_in[7];
    const float* b1_1 = (const float*)d_in[8];
    const float* W2_1 = (const float*)d_in[9];
    const float* b2_1 = (const float*)d_in[10];
    const float* W1_2 = (const float*)d_in[11];
    const float* b1_2 = (const float*)d_in[12];
    const float* W2_2 = (const float*)d_in[13];
    const float* b2_2 = (const float*)d_in[14];
    float* out = (float*)d_out;
    unsigned short* wpk = (unsigned short*)d_ws;   // needs 245760 B

    prepack<<<dim3(480), dim3(256), 0, stream>>>(W1_0, W2_0, W1_1, W2_1, W1_2, W2_2, wpk);
    fused_v3<<<dim3(1344), dim3(256), 0, stream>>>(
        x0, x1, x2, b1_0, b2_0, b1_1, b2_1, b1_2, b2_2, wpk, out);
}